// Round 6
// baseline (127.290 us; speedup 1.0000x reference)
//
#include <hip/hip_runtime.h>
#include <math.h>
#include <type_traits>

namespace {
constexpr int B = 4, S = 2048, E = 512, D = 64, H = 8;
constexpr int KD = 512;

typedef short bf8 __attribute__((ext_vector_type(8)));
typedef short bf4 __attribute__((ext_vector_type(4)));
typedef float f4 __attribute__((ext_vector_type(4)));

__device__ __forceinline__ short f2bf(float f) {
  union { float f; unsigned u; } v; v.f = f;
  const unsigned r = v.u + 0x7fffu + ((v.u >> 16) & 1u);  // RNE
  return (short)(r >> 16);
}

__device__ __forceinline__ void gload16(const void* g, void* l) {
  __builtin_amdgcn_global_load_lds(
      (const __attribute__((address_space(1))) unsigned int*)g,
      (__attribute__((address_space(3))) unsigned int*)l, 16, 0, 0);
}

// ---------------------------------------------------------------------------
// x (fp32) -> xb (bf16)
// ---------------------------------------------------------------------------
__global__ __launch_bounds__(256) void xb_kernel(const float* __restrict__ x,
                                                 short* __restrict__ xb) {
  const size_t i = ((size_t)blockIdx.x * 256 + threadIdx.x) * 8;
  const float4 v0 = *(const float4*)(x + i);
  const float4 v1 = *(const float4*)(x + i + 4);
  bf8 o;
  o[0] = f2bf(v0.x); o[1] = f2bf(v0.y); o[2] = f2bf(v0.z); o[3] = f2bf(v0.w);
  o[4] = f2bf(v1.x); o[5] = f2bf(v1.y); o[6] = f2bf(v1.z); o[7] = f2bf(v1.w);
  *(bf8*)(xb + i) = o;
}

// ---------------------------------------------------------------------------
// WcatT[cb*64+d][e] = Wsel(w)[h][e][d]   (K-major weight concat, bf16)
// ---------------------------------------------------------------------------
__global__ __launch_bounds__(256) void wcat_kernel(
    const float* __restrict__ Wq, const float* __restrict__ Wk,
    const float* __restrict__ Wvd, short* __restrict__ WcatT) {
  const int cb = blockIdx.x;
  const int e0 = blockIdx.y * 64;
  const int w = cb >> 3, h = cb & 7;
  const float* Wsel = (w == 0) ? Wq : (w == 1) ? Wk : Wvd;
  const float* Wp = Wsel + (size_t)h * E * D;
  __shared__ float T[64][65];
  const int tid = threadIdx.x;
#pragma unroll
  for (int i = 0; i < 4; ++i) {
    const int f = tid + i * 256;
    const int r = f >> 4, c4 = f & 15;
    const float4 v = *(const float4*)(Wp + (size_t)(e0 + r) * D + c4 * 4);
    T[r][c4 * 4 + 0] = v.x; T[r][c4 * 4 + 1] = v.y;
    T[r][c4 * 4 + 2] = v.z; T[r][c4 * 4 + 3] = v.w;
  }
  __syncthreads();
#pragma unroll
  for (int i = 0; i < 4; ++i) {
    const int f = tid + i * 256;
    const int dr = f >> 4, e4 = f & 15;
    bf4 o;
#pragma unroll
    for (int j = 0; j < 4; ++j) o[j] = f2bf(T[e4 * 4 + j][dr]);
    *(bf4*)(WcatT + (size_t)(cb * 64 + dr) * KD + e0 + e4 * 4) = o;
  }
}

// ---------------------------------------------------------------------------
// W2T[e][h*64+d] = Wvu[h][d][e] * Wo[h]   (K-major, bf16)
// ---------------------------------------------------------------------------
__global__ __launch_bounds__(256) void w2t_kernel(
    const float* __restrict__ Wvu, const float* __restrict__ Wo,
    short* __restrict__ W2T) {
  const int h = blockIdx.x;
  const int e0 = blockIdx.y * 64;
  const float wo = Wo[h];
  __shared__ float T[64][65];
  const int tid = threadIdx.x;
#pragma unroll
  for (int i = 0; i < 4; ++i) {
    const int f = tid + i * 256;
    const int r = f >> 4, c4 = f & 15;
    const float4 v = *(const float4*)(Wvu + ((size_t)h * D + r) * E + e0 + c4 * 4);
    T[r][c4 * 4 + 0] = v.x * wo; T[r][c4 * 4 + 1] = v.y * wo;
    T[r][c4 * 4 + 2] = v.z * wo; T[r][c4 * 4 + 3] = v.w * wo;
  }
  __syncthreads();
#pragma unroll
  for (int i = 0; i < 4; ++i) {
    const int f = tid + i * 256;
    const int er = f >> 4, d4 = f & 15;
    bf4 o;
#pragma unroll
    for (int j = 0; j < 4; ++j) o[j] = f2bf(T[d4 * 4 + j][er]);
    *(bf4*)(W2T + (size_t)(e0 + er) * KD + h * 64 + d4 * 4) = o;
  }
}

// ---------------------------------------------------------------------------
// bf16 MFMA GEMM.  MODE 0: proj -> Qb/Kb (row-major [bh][s][d]) and V^T
// (Vt[bh][d][s], bf4 packed stores).  MODE 1: out epilogue (fp32 row-major).
// ---------------------------------------------------------------------------
template <int MODE>
__global__ __launch_bounds__(256) void gemm_kernel(
    const short* __restrict__ A, const short* __restrict__ Bt,
    short* __restrict__ Qb, short* __restrict__ Kb, short* __restrict__ Vtg,
    float* __restrict__ Of) {
  const int row0 = blockIdx.x * 128;
  const int ct = blockIdx.y;
  const int tid = threadIdx.x;
  const int w = tid >> 6, l = tid & 63;
  const int wm = w >> 1, wn = w & 1;
  const int lr = l & 15, hi = l >> 4;

  __shared__ short As[128 * 64];
  __shared__ short Bs[128 * 64];

  const short* Ag = A + (size_t)row0 * KD;
  const short* Bg = Bt + (size_t)ct * 128 * KD;

  f4 acc[4][4] = {};
  for (int k0 = 0; k0 < KD; k0 += 64) {
    __syncthreads();
#pragma unroll
    for (int i = 0; i < 4; ++i) {
      const int f = i * 256 + tid;
      const int r = f >> 3, g = f & 7;
      gload16(Ag + (size_t)r * KD + k0 + ((g ^ (r & 7)) << 3), &As[f * 8]);
    }
#pragma unroll
    for (int i = 0; i < 4; ++i) {
      const int f = i * 256 + tid;
      const int r = f >> 3, g = f & 7;
      gload16(Bg + (size_t)r * KD + k0 + ((g ^ (r & 7)) << 3), &Bs[f * 8]);
    }
    __syncthreads();

    bf8 af[4][2], bfv[4][2];
#pragma unroll
    for (int t = 0; t < 4; ++t) {
#pragma unroll
      for (int kh = 0; kh < 2; ++kh) {
        const int ar = wm * 64 + t * 16 + lr;
        af[t][kh] = *(const bf8*)&As[ar * 64 + (((kh * 4 + hi) ^ (ar & 7)) << 3)];
        const int br = wn * 64 + t * 16 + lr;
        bfv[t][kh] = *(const bf8*)&Bs[br * 64 + (((kh * 4 + hi) ^ (br & 7)) << 3)];
      }
    }
#pragma unroll
    for (int mt = 0; mt < 4; ++mt)
#pragma unroll
      for (int nt = 0; nt < 4; ++nt) {
        acc[mt][nt] =
            __builtin_amdgcn_mfma_f32_16x16x32_bf16(af[mt][0], bfv[nt][0], acc[mt][nt], 0, 0, 0);
        acc[mt][nt] =
            __builtin_amdgcn_mfma_f32_16x16x32_bf16(af[mt][1], bfv[nt][1], acc[mt][nt], 0, 0, 0);
      }
  }

  if constexpr (MODE == 0) {
#pragma unroll
    for (int nt = 0; nt < 4; ++nt) {
      const int gc = ct * 128 + wn * 64 + nt * 16 + lr;
      const int cb = gc >> 6, d = gc & 63;
      const int h = cb & 7;
      if (cb < 16) {
        short* Out = (cb < 8) ? Qb : Kb;
#pragma unroll
        for (int mt = 0; mt < 4; ++mt)
#pragma unroll
          for (int reg = 0; reg < 4; ++reg) {
            const int grow = row0 + wm * 64 + mt * 16 + hi * 4 + reg;
            const int b = grow >> 11, s = grow & (S - 1);
            Out[(((size_t)(b * H + h) * S + s) << 6) + d] = f2bf(acc[mt][nt][reg]);
          }
      } else {
        // V^T: Vt[bh][d][s], 4 consecutive s per lane -> packed bf4 store
#pragma unroll
        for (int mt = 0; mt < 4; ++mt) {
          const int grow0 = row0 + wm * 64 + mt * 16 + hi * 4;
          const int b = grow0 >> 11, s0 = grow0 & (S - 1);
          bf4 o;
#pragma unroll
          for (int reg = 0; reg < 4; ++reg) o[reg] = f2bf(acc[mt][nt][reg]);
          *(bf4*)(Vtg + (((size_t)(b * H + h) * D + d) << 11) + s0) = o;
        }
      }
    }
  } else {
#pragma unroll
    for (int mt = 0; mt < 4; ++mt)
#pragma unroll
      for (int reg = 0; reg < 4; ++reg) {
        const int grow = row0 + wm * 64 + mt * 16 + hi * 4 + reg;
        float* orow = Of + (size_t)grow * 512 + ct * 128 + wn * 64;
#pragma unroll
        for (int nt = 0; nt < 4; ++nt) orow[nt * 16 + lr] = acc[mt][nt][reg];
      }
  }
}

// ---------------------------------------------------------------------------
// attn v3: BM=128 (2 q-frags/wave), fixed-max softmax (M=12), dbuf gload_lds.
// Masking replicates reference: (t<=q) && (raw score != 0), else p=0.
// ---------------------------------------------------------------------------
__global__ __launch_bounds__(256) void attn_kernel(
    const short* __restrict__ Qb, const short* __restrict__ Kb,
    const short* __restrict__ Vt, short* __restrict__ PVb) {
  const int bh = blockIdx.x;
  const int qt2 = (int)(gridDim.y - 1 - blockIdx.y);  // longest-first
  const int b = bh >> 3, h = bh & 7;
  const int tid = threadIdx.x;
  const int w = tid >> 6, l = tid & 63;
  const int lr = l & 15, hi = l >> 4;

  __shared__ short Ks[2][64 * 64];
  __shared__ short Vs[2][64 * 64];
  __shared__ short Ps[4][2][16 * 64];

  bf8 qf[2][2];
#pragma unroll
  for (int f = 0; f < 2; ++f) {
    const short* Qg =
        Qb + ((size_t)bh * S + qt2 * 128 + f * 64 + w * 16 + lr) * D;
    qf[f][0] = *(const bf8*)(Qg + hi * 8);
    qf[f][1] = *(const bf8*)(Qg + 32 + hi * 8);
  }

  const short* Kg = Kb + (size_t)bh * S * D;   // [t][64]
  const short* Vg = Vt + (size_t)bh * D * S;   // [e][S]

  const int sr = tid >> 3, sg = tid & 7;
  const int sswz = (sg ^ (sr & 7)) << 3;
  const int sr2 = sr + 32, sswz2 = (sg ^ (sr2 & 7)) << 3;

  float lsum[2][4] = {};
  f4 accO[2][4] = {};

  const int ktmax = 2 * qt2 + 1;

  // prologue: stage tile 0
  gload16(Kg + (size_t)sr * D + sswz, &Ks[0][tid * 8]);
  gload16(Kg + (size_t)sr2 * D + sswz2, &Ks[0][(256 + tid) * 8]);
  gload16(Vg + (size_t)sr * S + sswz, &Vs[0][tid * 8]);
  gload16(Vg + (size_t)sr2 * S + sswz2, &Vs[0][(256 + tid) * 8]);
  __syncthreads();

  constexpr float LOG2E = 1.44269504088896340736f;
  constexpr float C1 = 0.125f * LOG2E;
  constexpr float C0 = -12.0f * LOG2E;

  int buf = 0;
  for (int kt = 0; kt <= ktmax; ++kt) {
    if (kt < ktmax) {
      const int nb = buf ^ 1;
      const size_t koff = (size_t)(kt + 1) * 64;
      gload16(Kg + (koff + sr) * D + sswz, &Ks[nb][tid * 8]);
      gload16(Kg + (koff + sr2) * D + sswz2, &Ks[nb][(256 + tid) * 8]);
      gload16(Vg + (size_t)sr * S + koff + sswz, &Vs[nb][tid * 8]);
      gload16(Vg + (size_t)sr2 * S + koff + sswz2, &Vs[nb][(256 + tid) * 8]);
    }

    const short* Kl = Ks[buf];
    const short* Vl = Vs[buf];

    auto frag_step = [&](int f, f4* aO, float* ls, auto diag_c) {
      constexpr bool DIAG = decltype(diag_c)::value;
      f4 accS[4] = {};
      __builtin_amdgcn_s_setprio(1);
#pragma unroll
      for (int n = 0; n < 4; ++n) {
        const int tr = n * 16 + lr;
        const bf8 k0 = *(const bf8*)&Kl[tr * 64 + ((hi ^ (tr & 7)) << 3)];
        const bf8 k1 = *(const bf8*)&Kl[tr * 64 + (((4 + hi) ^ (tr & 7)) << 3)];
        accS[n] = __builtin_amdgcn_mfma_f32_16x16x32_bf16(qf[f][0], k0, accS[n], 0, 0, 0);
        accS[n] = __builtin_amdgcn_mfma_f32_16x16x32_bf16(qf[f][1], k1, accS[n], 0, 0, 0);
      }
      __builtin_amdgcn_s_setprio(0);

      short* Pw = Ps[w][f];
      const int qg0 = qt2 * 128 + f * 64 + w * 16 + hi * 4;
#pragma unroll
      for (int n = 0; n < 4; ++n) {
        const int g = 2 * n + (lr >> 3);
        const int tg = kt * 64 + n * 16 + lr;
        (void)tg;
#pragma unroll
        for (int reg = 0; reg < 4; ++reg) {
          const float sv = accS[n][reg];
          float p = exp2f(fmaf(sv, C1, C0));
          bool ok = (sv != 0.f);
          if constexpr (DIAG) ok = ok && (tg <= qg0 + reg);
          p = ok ? p : 0.f;
          ls[reg] += p;
          const int m = hi * 4 + reg;
          Pw[m * 64 + ((g ^ (m & 7)) << 3) + (lr & 7)] = f2bf(p);
        }
      }

      __builtin_amdgcn_s_setprio(1);
#pragma unroll
      for (int kh = 0; kh < 2; ++kh) {
        const bf8 pf = *(const bf8*)&Pw[lr * 64 + (((kh * 4 + hi) ^ (lr & 7)) << 3)];
#pragma unroll
        for (int n = 0; n < 4; ++n) {
          const int er = n * 16 + lr;
          const bf8 vf = *(const bf8*)&Vl[er * 64 + (((kh * 4 + hi) ^ (er & 7)) << 3)];
          aO[n] = __builtin_amdgcn_mfma_f32_16x16x32_bf16(pf, vf, aO[n], 0, 0, 0);
        }
      }
      __builtin_amdgcn_s_setprio(0);
    };

    // frag 0 (q rows [qt2*128, +64)): active while kt <= 2*qt2
    if (kt < 2 * qt2) {
      frag_step(0, accO[0], lsum[0], std::false_type{});
    } else if (kt == 2 * qt2) {
      frag_step(0, accO[0], lsum[0], std::true_type{});
    }
    // frag 1 (q rows [qt2*128+64, +64)): always active, diag on last tile
    if (kt < ktmax) {
      frag_step(1, accO[1], lsum[1], std::false_type{});
    } else {
      frag_step(1, accO[1], lsum[1], std::true_type{});
    }

    __syncthreads();  // drains vmcnt(0): prefetch complete; all waves synced
    buf ^= 1;
  }

  // epilogue: reduce lsum across the 16 t-lanes, normalize, store bf16
#pragma unroll
  for (int f = 0; f < 2; ++f) {
#pragma unroll
    for (int reg = 0; reg < 4; ++reg) {
      float lv = lsum[f][reg];
      lv += __shfl_xor(lv, 1);
      lv += __shfl_xor(lv, 2);
      lv += __shfl_xor(lv, 4);
      lv += __shfl_xor(lv, 8);
      const float inv = 1.f / lv;
      const int s = qt2 * 128 + f * 64 + w * 16 + hi * 4 + reg;
      short* op = PVb + (size_t)(b * S + s) * (H * D) + h * D;
#pragma unroll
      for (int n = 0; n < 4; ++n) op[n * 16 + lr] = f2bf(accO[f][n][reg] * inv);
    }
  }
}

}  // namespace

extern "C" void kernel_launch(void* const* d_in, const int* in_sizes, int n_in,
                              void* d_out, int out_size, void* d_ws, size_t ws_size,
                              hipStream_t stream) {
  const float* x   = (const float*)d_in[0];
  const float* Wq  = (const float*)d_in[1];
  const float* Wk  = (const float*)d_in[2];
  const float* Wvd = (const float*)d_in[3];
  const float* Wvu = (const float*)d_in[4];
  const float* Wo  = (const float*)d_in[5];
  float* out = (float*)d_out;

  const size_t nqk = (size_t)B * H * S * D;  // 4.19M
  short* xb    = (short*)d_ws;
  short* Qb    = xb + nqk;
  short* Kb    = Qb + nqk;
  short* Vtg   = Kb + nqk;
  short* PVb   = Vtg + nqk;
  short* WcatT = PVb + nqk;            // [1536][512]
  short* W2T   = WcatT + 1536 * KD;    // [512][512]

  xb_kernel<<<dim3(B * S * E / (256 * 8)), 256, 0, stream>>>(x, xb);
  wcat_kernel<<<dim3(24, 8), 256, 0, stream>>>(Wq, Wk, Wvd, WcatT);
  w2t_kernel<<<dim3(8, 8), 256, 0, stream>>>(Wvu, Wo, W2T);
  gemm_kernel<0><<<dim3(64, 12), 256, 0, stream>>>(xb, WcatT, Qb, Kb, Vtg, nullptr);
  attn_kernel<<<dim3(B * H, S / 128), 256, 0, stream>>>(Qb, Kb, Vtg, PVb);
  gemm_kernel<1><<<dim3(64, 4), 256, 0, stream>>>(PVb, W2T, nullptr, nullptr, nullptr, out);
}

// Round 7
// 94.038 us; speedup vs baseline: 1.3536x; 1.3536x over previous
//
#include <hip/hip_runtime.h>
#include <math.h>

namespace {
constexpr int B = 4, S = 2048, E = 512, D = 64, H = 8;
constexpr int KD = 512;

typedef short bf8 __attribute__((ext_vector_type(8)));
typedef short bf4 __attribute__((ext_vector_type(4)));
typedef float f4 __attribute__((ext_vector_type(4)));

__device__ __forceinline__ short f2bf(float f) {
  union { float f; unsigned u; } v; v.f = f;
  const unsigned r = v.u + 0x7fffu + ((v.u >> 16) & 1u);  // RNE
  return (short)(r >> 16);
}

__device__ __forceinline__ unsigned cvt_pk_bf16(float a, float b) {
  unsigned r;
  asm("v_cvt_pk_bf16_f32 %0, %1, %2" : "=v"(r) : "v"(a), "v"(b));
  return r;  // lo16 = bf16(a), hi16 = bf16(b)
}

__device__ __forceinline__ void gload16(const void* g, void* l) {
  __builtin_amdgcn_global_load_lds(
      (const __attribute__((address_space(1))) unsigned int*)g,
      (__attribute__((address_space(3))) unsigned int*)l, 16, 0, 0);
}

// ---------------------------------------------------------------------------
// x (fp32) -> xb (bf16)
// ---------------------------------------------------------------------------
__global__ __launch_bounds__(256) void xb_kernel(const float* __restrict__ x,
                                                 short* __restrict__ xb) {
  const size_t i = ((size_t)blockIdx.x * 256 + threadIdx.x) * 8;
  const float4 v0 = *(const float4*)(x + i);
  const float4 v1 = *(const float4*)(x + i + 4);
  bf8 o;
  o[0] = f2bf(v0.x); o[1] = f2bf(v0.y); o[2] = f2bf(v0.z); o[3] = f2bf(v0.w);
  o[4] = f2bf(v1.x); o[5] = f2bf(v1.y); o[6] = f2bf(v1.z); o[7] = f2bf(v1.w);
  *(bf8*)(xb + i) = o;
}

// ---------------------------------------------------------------------------
// WcatT[cb*64+d][e] = Wsel(w)[h][e][d]   (K-major weight concat, bf16)
// ---------------------------------------------------------------------------
__global__ __launch_bounds__(256) void wcat_kernel(
    const float* __restrict__ Wq, const float* __restrict__ Wk,
    const float* __restrict__ Wvd, short* __restrict__ WcatT) {
  const int cb = blockIdx.x;
  const int e0 = blockIdx.y * 64;
  const int w = cb >> 3, h = cb & 7;
  const float* Wsel = (w == 0) ? Wq : (w == 1) ? Wk : Wvd;
  const float* Wp = Wsel + (size_t)h * E * D;
  __shared__ float T[64][65];
  const int tid = threadIdx.x;
#pragma unroll
  for (int i = 0; i < 4; ++i) {
    const int f = tid + i * 256;
    const int r = f >> 4, c4 = f & 15;
    const float4 v = *(const float4*)(Wp + (size_t)(e0 + r) * D + c4 * 4);
    T[r][c4 * 4 + 0] = v.x; T[r][c4 * 4 + 1] = v.y;
    T[r][c4 * 4 + 2] = v.z; T[r][c4 * 4 + 3] = v.w;
  }
  __syncthreads();
#pragma unroll
  for (int i = 0; i < 4; ++i) {
    const int f = tid + i * 256;
    const int dr = f >> 4, e4 = f & 15;
    bf4 o;
#pragma unroll
    for (int j = 0; j < 4; ++j) o[j] = f2bf(T[e4 * 4 + j][dr]);
    *(bf4*)(WcatT + (size_t)(cb * 64 + dr) * KD + e0 + e4 * 4) = o;
  }
}

// ---------------------------------------------------------------------------
// W2T[e][h*64+d] = Wvu[h][d][e] * Wo[h]   (K-major, bf16)
// ---------------------------------------------------------------------------
__global__ __launch_bounds__(256) void w2t_kernel(
    const float* __restrict__ Wvu, const float* __restrict__ Wo,
    short* __restrict__ W2T) {
  const int h = blockIdx.x;
  const int e0 = blockIdx.y * 64;
  const float wo = Wo[h];
  __shared__ float T[64][65];
  const int tid = threadIdx.x;
#pragma unroll
  for (int i = 0; i < 4; ++i) {
    const int f = tid + i * 256;
    const int r = f >> 4, c4 = f & 15;
    const float4 v = *(const float4*)(Wvu + ((size_t)h * D + r) * E + e0 + c4 * 4);
    T[r][c4 * 4 + 0] = v.x * wo; T[r][c4 * 4 + 1] = v.y * wo;
    T[r][c4 * 4 + 2] = v.z * wo; T[r][c4 * 4 + 3] = v.w * wo;
  }
  __syncthreads();
#pragma unroll
  for (int i = 0; i < 4; ++i) {
    const int f = tid + i * 256;
    const int er = f >> 4, d4 = f & 15;
    bf4 o;
#pragma unroll
    for (int j = 0; j < 4; ++j) o[j] = f2bf(T[d4 * 4 + j][er]);
    *(bf4*)(W2T + (size_t)(e0 + er) * KD + h * 64 + d4 * 4) = o;
  }
}

// ---------------------------------------------------------------------------
// bf16 MFMA GEMM.  MODE 0: proj -> Qb/Kb (row-major [bh][s][d]) and V^T
// (Vt[bh][d][s], bf4 packed stores).  MODE 1: out epilogue (fp32 row-major).
// ---------------------------------------------------------------------------
template <int MODE>
__global__ __launch_bounds__(256) void gemm_kernel(
    const short* __restrict__ A, const short* __restrict__ Bt,
    short* __restrict__ Qb, short* __restrict__ Kb, short* __restrict__ Vtg,
    float* __restrict__ Of) {
  const int row0 = blockIdx.x * 128;
  const int ct = blockIdx.y;
  const int tid = threadIdx.x;
  const int w = tid >> 6, l = tid & 63;
  const int wm = w >> 1, wn = w & 1;
  const int lr = l & 15, hi = l >> 4;

  __shared__ short As[128 * 64];
  __shared__ short Bs[128 * 64];

  const short* Ag = A + (size_t)row0 * KD;
  const short* Bg = Bt + (size_t)ct * 128 * KD;

  f4 acc[4][4] = {};
  for (int k0 = 0; k0 < KD; k0 += 64) {
    __syncthreads();
#pragma unroll
    for (int i = 0; i < 4; ++i) {
      const int f = i * 256 + tid;
      const int r = f >> 3, g = f & 7;
      gload16(Ag + (size_t)r * KD + k0 + ((g ^ (r & 7)) << 3), &As[f * 8]);
    }
#pragma unroll
    for (int i = 0; i < 4; ++i) {
      const int f = i * 256 + tid;
      const int r = f >> 3, g = f & 7;
      gload16(Bg + (size_t)r * KD + k0 + ((g ^ (r & 7)) << 3), &Bs[f * 8]);
    }
    __syncthreads();

    bf8 af[4][2], bfv[4][2];
#pragma unroll
    for (int t = 0; t < 4; ++t) {
#pragma unroll
      for (int kh = 0; kh < 2; ++kh) {
        const int ar = wm * 64 + t * 16 + lr;
        af[t][kh] = *(const bf8*)&As[ar * 64 + (((kh * 4 + hi) ^ (ar & 7)) << 3)];
        const int br = wn * 64 + t * 16 + lr;
        bfv[t][kh] = *(const bf8*)&Bs[br * 64 + (((kh * 4 + hi) ^ (br & 7)) << 3)];
      }
    }
#pragma unroll
    for (int mt = 0; mt < 4; ++mt)
#pragma unroll
      for (int nt = 0; nt < 4; ++nt) {
        acc[mt][nt] =
            __builtin_amdgcn_mfma_f32_16x16x32_bf16(af[mt][0], bfv[nt][0], acc[mt][nt], 0, 0, 0);
        acc[mt][nt] =
            __builtin_amdgcn_mfma_f32_16x16x32_bf16(af[mt][1], bfv[nt][1], acc[mt][nt], 0, 0, 0);
      }
  }

  if constexpr (MODE == 0) {
#pragma unroll
    for (int nt = 0; nt < 4; ++nt) {
      const int gc = ct * 128 + wn * 64 + nt * 16 + lr;
      const int cb = gc >> 6, d = gc & 63;
      const int h = cb & 7;
      if (cb < 16) {
        short* Out = (cb < 8) ? Qb : Kb;
#pragma unroll
        for (int mt = 0; mt < 4; ++mt)
#pragma unroll
          for (int reg = 0; reg < 4; ++reg) {
            const int grow = row0 + wm * 64 + mt * 16 + hi * 4 + reg;
            const int b = grow >> 11, s = grow & (S - 1);
            Out[(((size_t)(b * H + h) * S + s) << 6) + d] = f2bf(acc[mt][nt][reg]);
          }
      } else {
        // V^T: Vt[bh][d][s], 4 consecutive s per lane -> packed bf4 store
#pragma unroll
        for (int mt = 0; mt < 4; ++mt) {
          const int grow0 = row0 + wm * 64 + mt * 16 + hi * 4;
          const int b = grow0 >> 11, s0 = grow0 & (S - 1);
          bf4 o;
#pragma unroll
          for (int reg = 0; reg < 4; ++reg) o[reg] = f2bf(acc[mt][nt][reg]);
          *(bf4*)(Vtg + (((size_t)(b * H + h) * D + d) << 11) + s0) = o;
        }
      }
    }
  } else {
#pragma unroll
    for (int mt = 0; mt < 4; ++mt)
#pragma unroll
      for (int reg = 0; reg < 4; ++reg) {
        const int grow = row0 + wm * 64 + mt * 16 + hi * 4 + reg;
        float* orow = Of + (size_t)grow * 512 + ct * 128 + wn * 64;
#pragma unroll
        for (int nt = 0; nt < 4; ++nt) orow[nt * 16 + lr] = acc[mt][nt][reg];
      }
  }
}

// ---------------------------------------------------------------------------
// attn v4: BM=64, swapped QK^T (lane holds 4 consecutive t per q), fixed-max
// softmax M=12, cvt_pk P-pack + b64 writes, dbuf gload_lds staging.
// Masking replicates reference: (t<=q) && (raw score != 0), else p=0.
// ---------------------------------------------------------------------------
__global__ __launch_bounds__(256) void attn_kernel(
    const short* __restrict__ Qb, const short* __restrict__ Kb,
    const short* __restrict__ Vt, short* __restrict__ PVb) {
  const int bh = blockIdx.x;
  const int qt = (int)(gridDim.y - 1 - blockIdx.y);  // longest-first
  const int b = bh >> 3, h = bh & 7;
  const int tid = threadIdx.x;
  const int w = tid >> 6, l = tid & 63;
  const int lr = l & 15, hi = l >> 4;

  __shared__ short Ks[2][64 * 64];
  __shared__ short Vs[2][64 * 64];
  __shared__ short Ps[4][16 * 64];

  // Q fragment (B operand after swap): col q = lr, k = kh*32 + hi*8 + j
  const short* Qg = Qb + ((size_t)bh * S + qt * 64 + w * 16 + lr) * D;
  const bf8 qf0 = *(const bf8*)(Qg + hi * 8);
  const bf8 qf1 = *(const bf8*)(Qg + 32 + hi * 8);

  const short* Kg = Kb + (size_t)bh * S * D;   // [t][64]
  const short* Vg = Vt + (size_t)bh * D * S;   // [e][S]

  const int sr = tid >> 3, sg = tid & 7;
  const int sswz = (sg ^ (sr & 7)) << 3;
  const int sr2 = sr + 32, sswz2 = (sg ^ (sr2 & 7)) << 3;

  float lsum = 0.f;   // per-lane partial denominator for q = lr
  f4 accO[4] = {};    // O[q = hi*4+reg][e = n*16+lr]

  constexpr float LOG2E = 1.44269504088896340736f;
  constexpr float C1 = 0.125f * LOG2E;
  constexpr float C0 = -12.0f * LOG2E;

  short* Pw = Ps[w];
  const int c7 = lr & 7;

  // prologue: stage tile 0
  gload16(Kg + (size_t)sr * D + sswz, &Ks[0][tid * 8]);
  gload16(Kg + (size_t)sr2 * D + sswz2, &Ks[0][(256 + tid) * 8]);
  gload16(Vg + (size_t)sr * S + sswz, &Vs[0][tid * 8]);
  gload16(Vg + (size_t)sr2 * S + sswz2, &Vs[0][(256 + tid) * 8]);
  __syncthreads();

  auto step = [&](const short* Kl, const short* Vl, auto diag_c) {
    constexpr bool DIAG = decltype(diag_c)::value;
    // QK^T swapped: A = K (rows t), B = Q (cols q) -> D[t][q]
    f4 accS[4] = {};
    __builtin_amdgcn_s_setprio(1);
#pragma unroll
    for (int n = 0; n < 4; ++n) {
      const int tr = n * 16 + lr;
      const bf8 k0 = *(const bf8*)&Kl[tr * 64 + ((hi ^ (tr & 7)) << 3)];
      const bf8 k1 = *(const bf8*)&Kl[tr * 64 + (((4 + hi) ^ (tr & 7)) << 3)];
      accS[n] = __builtin_amdgcn_mfma_f32_16x16x32_bf16(k0, qf0, accS[n], 0, 0, 0);
      accS[n] = __builtin_amdgcn_mfma_f32_16x16x32_bf16(k1, qf1, accS[n], 0, 0, 0);
    }
    __builtin_amdgcn_s_setprio(0);

    // p = exp2(sv*C1 + C0), masked; lane's 4 regs = 4 consecutive t, q = lr
#pragma unroll
    for (int n = 0; n < 4; ++n) {
      float p[4];
#pragma unroll
      for (int reg = 0; reg < 4; ++reg) {
        const float sv = accS[n][reg];
        bool ok = (sv != 0.f);
        if constexpr (DIAG) ok = ok && (n * 16 + hi * 4 + reg <= w * 16 + lr);
        p[reg] = ok ? exp2f(fmaf(sv, C1, C0)) : 0.f;
        lsum += p[reg];
      }
      // pack 4 bf16 (consecutive t) -> one b64 store
      int2 pk;
      pk.x = (int)cvt_pk_bf16(p[0], p[1]);
      pk.y = (int)cvt_pk_bf16(p[2], p[3]);
      const int gi = 2 * n + (hi >> 1);               // t granule (8 shorts)
      *(int2*)&Pw[lr * 64 + ((gi ^ c7) << 3) + (hi & 1) * 4] = pk;
    }

    // PV: A = P[q=lr][t], B = Vt[e][t] -> O[q][e]
    __builtin_amdgcn_s_setprio(1);
#pragma unroll
    for (int kh = 0; kh < 2; ++kh) {
      const bf8 pf = *(const bf8*)&Pw[lr * 64 + (((kh * 4 + hi) ^ c7) << 3)];
#pragma unroll
      for (int n = 0; n < 4; ++n) {
        const int er = n * 16 + lr;
        const bf8 vf = *(const bf8*)&Vl[er * 64 + (((kh * 4 + hi) ^ (er & 7)) << 3)];
        accO[n] = __builtin_amdgcn_mfma_f32_16x16x32_bf16(pf, vf, accO[n], 0, 0, 0);
      }
    }
    __builtin_amdgcn_s_setprio(0);
  };

  int buf = 0;
  for (int kt = 0; kt <= qt; ++kt) {
    if (kt < qt) {  // prefetch next tile into other buffer
      const int nb = buf ^ 1;
      const size_t koff = (size_t)(kt + 1) * 64;
      gload16(Kg + (koff + sr) * D + sswz, &Ks[nb][tid * 8]);
      gload16(Kg + (koff + sr2) * D + sswz2, &Ks[nb][(256 + tid) * 8]);
      gload16(Vg + (size_t)sr * S + koff + sswz, &Vs[nb][tid * 8]);
      gload16(Vg + (size_t)sr2 * S + koff + sswz2, &Vs[nb][(256 + tid) * 8]);
    }
    if (kt < qt) {
      step(Ks[buf], Vs[buf], std::integral_constant<bool, false>{});
    } else {
      step(Ks[buf], Vs[buf], std::integral_constant<bool, true>{});
    }
    __syncthreads();  // drains vmcnt(0): prefetch complete; all waves synced
    buf ^= 1;
  }

  // epilogue: finish denominator (sum over hi-groups), redistribute, store
  float lv = lsum;
  lv += __shfl_xor(lv, 16);
  lv += __shfl_xor(lv, 32);   // all lanes now hold full sum for q = lr
#pragma unroll
  for (int reg = 0; reg < 4; ++reg) {
    const float lq = __shfl(lv, hi * 4 + reg);  // sum for q = hi*4+reg
    const float inv = 1.f / lq;
    const int s = qt * 64 + w * 16 + hi * 4 + reg;
    short* op = PVb + (size_t)(b * S + s) * (H * D) + h * D;
#pragma unroll
    for (int n = 0; n < 4; ++n) op[n * 16 + lr] = f2bf(accO[n][reg] * inv);
  }
}

}  // namespace

extern "C" void kernel_launch(void* const* d_in, const int* in_sizes, int n_in,
                              void* d_out, int out_size, void* d_ws, size_t ws_size,
                              hipStream_t stream) {
  const float* x   = (const float*)d_in[0];
  const float* Wq  = (const float*)d_in[1];
  const float* Wk  = (const float*)d_in[2];
  const float* Wvd = (const float*)d_in[3];
  const float* Wvu = (const float*)d_in[4];
  const float* Wo  = (const float*)d_in[5];
  float* out = (float*)d_out;

  const size_t nqk = (size_t)B * H * S * D;  // 4.19M
  short* xb    = (short*)d_ws;
  short* Qb    = xb + nqk;
  short* Kb    = Qb + nqk;
  short* Vtg   = Kb + nqk;
  short* PVb   = Vtg + nqk;
  short* WcatT = PVb + nqk;            // [1536][512]
  short* W2T   = WcatT + 1536 * KD;    // [512][512]

  xb_kernel<<<dim3(B * S * E / (256 * 8)), 256, 0, stream>>>(x, xb);
  wcat_kernel<<<dim3(24, 8), 256, 0, stream>>>(Wq, Wk, Wvd, WcatT);
  w2t_kernel<<<dim3(8, 8), 256, 0, stream>>>(Wvu, Wo, W2T);
  gemm_kernel<0><<<dim3(64, 12), 256, 0, stream>>>(xb, WcatT, Qb, Kb, Vtg, nullptr);
  attn_kernel<<<dim3(B * H, S / 64), 256, 0, stream>>>(Qb, Kb, Vtg, PVb);
  gemm_kernel<1><<<dim3(64, 4), 256, 0, stream>>>(PVb, W2T, nullptr, nullptr, nullptr, out);
}

// Round 8
// 85.620 us; speedup vs baseline: 1.4867x; 1.0983x over previous
//
#include <hip/hip_runtime.h>
#include <math.h>
#include <type_traits>

namespace {
constexpr int B = 4, S = 2048, E = 512, D = 64, H = 8;
constexpr int KD = 512;

typedef short bf8 __attribute__((ext_vector_type(8)));
typedef short bf4 __attribute__((ext_vector_type(4)));
typedef float f4 __attribute__((ext_vector_type(4)));

__device__ __forceinline__ short f2bf(float f) {
  union { float f; unsigned u; } v; v.f = f;
  const unsigned r = v.u + 0x7fffu + ((v.u >> 16) & 1u);  // RNE
  return (short)(r >> 16);
}

__device__ __forceinline__ unsigned cvt_pk_bf16(float a, float b) {
  unsigned r;
  asm("v_cvt_pk_bf16_f32 %0, %1, %2" : "=v"(r) : "v"(a), "v"(b));
  return r;  // lo16 = bf16(a), hi16 = bf16(b)
}

__device__ __forceinline__ void gload16(const void* g, void* l) {
  __builtin_amdgcn_global_load_lds(
      (const __attribute__((address_space(1))) unsigned int*)g,
      (__attribute__((address_space(3))) unsigned int*)l, 16, 0, 0);
}

// ---------------------------------------------------------------------------
// fused prep: [0,2048) xb convert; [2048,2240) WcatT; [2240,2304) W2T
// ---------------------------------------------------------------------------
__global__ __launch_bounds__(256) void prep_kernel(
    const float* __restrict__ x, const float* __restrict__ Wq,
    const float* __restrict__ Wk, const float* __restrict__ Wvd,
    const float* __restrict__ Wvu, const float* __restrict__ Wo,
    short* __restrict__ xb, short* __restrict__ WcatT,
    short* __restrict__ W2T) {
  __shared__ float T[64][65];
  const int bid = blockIdx.x;
  const int tid = threadIdx.x;
  if (bid < 2048) {
    const size_t i = ((size_t)bid * 256 + tid) * 8;
    const float4 v0 = *(const float4*)(x + i);
    const float4 v1 = *(const float4*)(x + i + 4);
    bf8 o;
    o[0] = f2bf(v0.x); o[1] = f2bf(v0.y); o[2] = f2bf(v0.z); o[3] = f2bf(v0.w);
    o[4] = f2bf(v1.x); o[5] = f2bf(v1.y); o[6] = f2bf(v1.z); o[7] = f2bf(v1.w);
    *(bf8*)(xb + i) = o;
  } else if (bid < 2240) {
    const int r = bid - 2048;
    const int cb = r >> 3, e0 = (r & 7) * 64;
    const int w = cb >> 3, h = cb & 7;
    const float* Wsel = (w == 0) ? Wq : (w == 1) ? Wk : Wvd;
    const float* Wp = Wsel + (size_t)h * E * D;
#pragma unroll
    for (int i = 0; i < 4; ++i) {
      const int f = tid + i * 256;
      const int rr = f >> 4, c4 = f & 15;
      const float4 v = *(const float4*)(Wp + (size_t)(e0 + rr) * D + c4 * 4);
      T[rr][c4 * 4 + 0] = v.x; T[rr][c4 * 4 + 1] = v.y;
      T[rr][c4 * 4 + 2] = v.z; T[rr][c4 * 4 + 3] = v.w;
    }
    __syncthreads();
#pragma unroll
    for (int i = 0; i < 4; ++i) {
      const int f = tid + i * 256;
      const int dr = f >> 4, e4 = f & 15;
      bf4 o;
#pragma unroll
      for (int j = 0; j < 4; ++j) o[j] = f2bf(T[e4 * 4 + j][dr]);
      *(bf4*)(WcatT + (size_t)(cb * 64 + dr) * KD + e0 + e4 * 4) = o;
    }
  } else {
    const int r = bid - 2240;
    const int h = r >> 3, e0 = (r & 7) * 64;
    const float wo = Wo[h];
#pragma unroll
    for (int i = 0; i < 4; ++i) {
      const int f = tid + i * 256;
      const int rr = f >> 4, c4 = f & 15;
      const float4 v = *(const float4*)(Wvu + ((size_t)h * D + rr) * E + e0 + c4 * 4);
      T[rr][c4 * 4 + 0] = v.x * wo; T[rr][c4 * 4 + 1] = v.y * wo;
      T[rr][c4 * 4 + 2] = v.z * wo; T[rr][c4 * 4 + 3] = v.w * wo;
    }
    __syncthreads();
#pragma unroll
    for (int i = 0; i < 4; ++i) {
      const int f = tid + i * 256;
      const int er = f >> 4, d4 = f & 15;
      bf4 o;
#pragma unroll
      for (int j = 0; j < 4; ++j) o[j] = f2bf(T[d4 * 4 + j][er]);
      *(bf4*)(W2T + (size_t)(e0 + er) * KD + h * 64 + d4 * 4) = o;
    }
  }
}

// ---------------------------------------------------------------------------
// bf16 MFMA GEMM.  MODE 0: proj -> Qb/Kb (row-major [bh][s][d]) and V^T
// (Vt[bh][d][s], bf4 packed stores).  MODE 1: out epilogue (fp32 row-major).
// ---------------------------------------------------------------------------
template <int MODE>
__global__ __launch_bounds__(256) void gemm_kernel(
    const short* __restrict__ A, const short* __restrict__ Bt,
    short* __restrict__ Qb, short* __restrict__ Kb, short* __restrict__ Vtg,
    float* __restrict__ Of) {
  const int row0 = blockIdx.x * 128;
  const int ct = blockIdx.y;
  const int tid = threadIdx.x;
  const int w = tid >> 6, l = tid & 63;
  const int wm = w >> 1, wn = w & 1;
  const int lr = l & 15, hi = l >> 4;

  __shared__ short As[128 * 64];
  __shared__ short Bs[128 * 64];

  const short* Ag = A + (size_t)row0 * KD;
  const short* Bg = Bt + (size_t)ct * 128 * KD;

  f4 acc[4][4] = {};
  for (int k0 = 0; k0 < KD; k0 += 64) {
    __syncthreads();
#pragma unroll
    for (int i = 0; i < 4; ++i) {
      const int f = i * 256 + tid;
      const int r = f >> 3, g = f & 7;
      gload16(Ag + (size_t)r * KD + k0 + ((g ^ (r & 7)) << 3), &As[f * 8]);
    }
#pragma unroll
    for (int i = 0; i < 4; ++i) {
      const int f = i * 256 + tid;
      const int r = f >> 3, g = f & 7;
      gload16(Bg + (size_t)r * KD + k0 + ((g ^ (r & 7)) << 3), &Bs[f * 8]);
    }
    __syncthreads();

    bf8 af[4][2], bfv[4][2];
#pragma unroll
    for (int t = 0; t < 4; ++t) {
#pragma unroll
      for (int kh = 0; kh < 2; ++kh) {
        const int ar = wm * 64 + t * 16 + lr;
        af[t][kh] = *(const bf8*)&As[ar * 64 + (((kh * 4 + hi) ^ (ar & 7)) << 3)];
        const int br = wn * 64 + t * 16 + lr;
        bfv[t][kh] = *(const bf8*)&Bs[br * 64 + (((kh * 4 + hi) ^ (br & 7)) << 3)];
      }
    }
#pragma unroll
    for (int mt = 0; mt < 4; ++mt)
#pragma unroll
      for (int nt = 0; nt < 4; ++nt) {
        acc[mt][nt] =
            __builtin_amdgcn_mfma_f32_16x16x32_bf16(af[mt][0], bfv[nt][0], acc[mt][nt], 0, 0, 0);
        acc[mt][nt] =
            __builtin_amdgcn_mfma_f32_16x16x32_bf16(af[mt][1], bfv[nt][1], acc[mt][nt], 0, 0, 0);
      }
  }

  if constexpr (MODE == 0) {
#pragma unroll
    for (int nt = 0; nt < 4; ++nt) {
      const int gc = ct * 128 + wn * 64 + nt * 16 + lr;
      const int cb = gc >> 6, d = gc & 63;
      const int h = cb & 7;
      if (cb < 16) {
        short* Out = (cb < 8) ? Qb : Kb;
#pragma unroll
        for (int mt = 0; mt < 4; ++mt)
#pragma unroll
          for (int reg = 0; reg < 4; ++reg) {
            const int grow = row0 + wm * 64 + mt * 16 + hi * 4 + reg;
            const int b = grow >> 11, s = grow & (S - 1);
            Out[(((size_t)(b * H + h) * S + s) << 6) + d] = f2bf(acc[mt][nt][reg]);
          }
      } else {
        // V^T: Vt[bh][d][s], 4 consecutive s per lane -> packed bf4 store
#pragma unroll
        for (int mt = 0; mt < 4; ++mt) {
          const int grow0 = row0 + wm * 64 + mt * 16 + hi * 4;
          const int b = grow0 >> 11, s0 = grow0 & (S - 1);
          bf4 o;
#pragma unroll
          for (int reg = 0; reg < 4; ++reg) o[reg] = f2bf(acc[mt][nt][reg]);
          *(bf4*)(Vtg + (((size_t)(b * H + h) * D + d) << 11) + s0) = o;
        }
      }
    }
  } else {
#pragma unroll
    for (int mt = 0; mt < 4; ++mt)
#pragma unroll
      for (int reg = 0; reg < 4; ++reg) {
        const int grow = row0 + wm * 64 + mt * 16 + hi * 4 + reg;
        float* orow = Of + (size_t)grow * 512 + ct * 128 + wn * 64;
#pragma unroll
        for (int nt = 0; nt < 4; ++nt) orow[nt * 16 + lr] = acc[mt][nt][reg];
      }
  }
}

// ---------------------------------------------------------------------------
// attn v5: swapped QK^T + fixed-max softmax + counted-vmcnt dbuf pipeline.
// Per iter: barrier (old buffer free) -> issue 4 gload_lds (next tile) ->
// vmcnt(4) (current tile's loads done; issued a full phase ago) -> barrier
// (all waves' loads visible) -> compute. No full drain in the loop.
// Masking replicates reference: (t<=q) && (raw score != 0), else p=0.
// ---------------------------------------------------------------------------
__global__ __launch_bounds__(256) void attn_kernel(
    const short* __restrict__ Qb, const short* __restrict__ Kb,
    const short* __restrict__ Vt, short* __restrict__ PVb) {
  const int bh = blockIdx.x;
  const int qt = (int)(gridDim.y - 1 - blockIdx.y);  // longest-first
  const int b = bh >> 3, h = bh & 7;
  const int tid = threadIdx.x;
  const int w = tid >> 6, l = tid & 63;
  const int lr = l & 15, hi = l >> 4;

  __shared__ short KsA[64 * 64];
  __shared__ short KsB[64 * 64];
  __shared__ short VsA[64 * 64];
  __shared__ short VsB[64 * 64];
  __shared__ short Ps[4][16 * 64];

  // Q fragment (B operand after swap): col q = lr, k = kh*32 + hi*8 + j
  const short* Qg = Qb + ((size_t)bh * S + qt * 64 + w * 16 + lr) * D;
  const bf8 qf0 = *(const bf8*)(Qg + hi * 8);
  const bf8 qf1 = *(const bf8*)(Qg + 32 + hi * 8);

  const short* Kg = Kb + (size_t)bh * S * D;   // [t][64]
  const short* Vg = Vt + (size_t)bh * D * S;   // [e][S]

  const int sr = tid >> 3, sg = tid & 7;
  const int sswz = (sg ^ (sr & 7)) << 3;
  const int sr2 = sr + 32, sswz2 = (sg ^ (sr2 & 7)) << 3;

  // staging pointers, advanced by one tile per iteration
  const short* kg0 = Kg + (size_t)sr * D + sswz;
  const short* kg1 = Kg + (size_t)sr2 * D + sswz2;
  const short* vg0 = Vg + (size_t)sr * S + sswz;
  const short* vg1 = Vg + (size_t)sr2 * S + sswz2;

  float lsum = 0.f;   // per-lane partial denominator for q = lr
  f4 accO[4] = {};    // O[q = hi*4+reg][e = n*16+lr]

  constexpr float LOG2E = 1.44269504088896340736f;
  constexpr float C1 = 0.125f * LOG2E;
  constexpr float C0 = -12.0f * LOG2E;

  short* Pw = Ps[w];
  const int c7 = lr & 7;

  auto step = [&](const short* Kl, const short* Vl, auto diag_c) {
    constexpr bool DIAG = decltype(diag_c)::value;
    // QK^T swapped: A = K (rows t), B = Q (cols q) -> D[t][q]
    f4 accS[4] = {};
    __builtin_amdgcn_s_setprio(1);
#pragma unroll
    for (int n = 0; n < 4; ++n) {
      const int tr = n * 16 + lr;
      const bf8 k0 = *(const bf8*)&Kl[tr * 64 + ((hi ^ (tr & 7)) << 3)];
      const bf8 k1 = *(const bf8*)&Kl[tr * 64 + (((4 + hi) ^ (tr & 7)) << 3)];
      accS[n] = __builtin_amdgcn_mfma_f32_16x16x32_bf16(k0, qf0, accS[n], 0, 0, 0);
      accS[n] = __builtin_amdgcn_mfma_f32_16x16x32_bf16(k1, qf1, accS[n], 0, 0, 0);
    }
    __builtin_amdgcn_s_setprio(0);

    // p = exp2(sv*C1 + C0), masked; lane's 4 regs = 4 consecutive t, q = lr
#pragma unroll
    for (int n = 0; n < 4; ++n) {
      float p[4];
#pragma unroll
      for (int reg = 0; reg < 4; ++reg) {
        const float sv = accS[n][reg];
        bool ok = (sv != 0.f);
        if constexpr (DIAG) ok = ok && (n * 16 + hi * 4 + reg <= w * 16 + lr);
        p[reg] = ok ? exp2f(fmaf(sv, C1, C0)) : 0.f;
        lsum += p[reg];
      }
      // pack 4 bf16 (consecutive t) -> one b64 store
      int2 pk;
      pk.x = (int)cvt_pk_bf16(p[0], p[1]);
      pk.y = (int)cvt_pk_bf16(p[2], p[3]);
      const int gi = 2 * n + (hi >> 1);               // t granule (8 shorts)
      *(int2*)&Pw[lr * 64 + ((gi ^ c7) << 3) + (hi & 1) * 4] = pk;
    }

    // PV: A = P[q=lr][t], B = Vt[e][t] -> O[q][e]
    __builtin_amdgcn_s_setprio(1);
#pragma unroll
    for (int kh = 0; kh < 2; ++kh) {
      const bf8 pf = *(const bf8*)&Pw[lr * 64 + (((kh * 4 + hi) ^ c7) << 3)];
#pragma unroll
      for (int n = 0; n < 4; ++n) {
        const int er = n * 16 + lr;
        const bf8 vf = *(const bf8*)&Vl[er * 64 + (((kh * 4 + hi) ^ (er & 7)) << 3)];
        accO[n] = __builtin_amdgcn_mfma_f32_16x16x32_bf16(pf, vf, accO[n], 0, 0, 0);
      }
    }
    __builtin_amdgcn_s_setprio(0);
  };

  // prologue: issue tile-0 loads
  gload16(kg0, &KsA[tid * 8]);
  gload16(kg1, &KsA[(256 + tid) * 8]);
  gload16(vg0, &VsA[tid * 8]);
  gload16(vg1, &VsA[(256 + tid) * 8]);
  kg0 += 64 * D; kg1 += 64 * D; vg0 += 64; vg1 += 64;

  short* Kc = KsA; short* Vc = VsA;
  short* Kn = KsB; short* Vn = VsB;

  for (int kt = 0; kt <= qt; ++kt) {
    if (kt > 0) {
      __builtin_amdgcn_s_barrier();   // all waves done reading Kn/Vn's old data
      __builtin_amdgcn_sched_barrier(0);
    }
    if (kt < qt) {
      gload16(kg0, &Kn[tid * 8]);
      gload16(kg1, &Kn[(256 + tid) * 8]);
      gload16(vg0, &Vn[tid * 8]);
      gload16(vg1, &Vn[(256 + tid) * 8]);
      kg0 += 64 * D; kg1 += 64 * D; vg0 += 64; vg1 += 64;
      asm volatile("s_waitcnt vmcnt(4)" ::: "memory");  // tile-kt loads done
    } else {
      asm volatile("s_waitcnt vmcnt(0)" ::: "memory");
    }
    __builtin_amdgcn_sched_barrier(0);
    __builtin_amdgcn_s_barrier();     // all waves' tile-kt loads visible
    __builtin_amdgcn_sched_barrier(0);

    if (kt < qt) {
      step(Kc, Vc, std::integral_constant<bool, false>{});
    } else {
      step(Kc, Vc, std::integral_constant<bool, true>{});
    }
    { short* t = Kc; Kc = Kn; Kn = t; t = Vc; Vc = Vn; Vn = t; }
  }

  // epilogue: finish denominator (sum over hi-groups), redistribute, store
  float lv = lsum;
  lv += __shfl_xor(lv, 16);
  lv += __shfl_xor(lv, 32);   // all lanes now hold full sum for q = lr
#pragma unroll
  for (int reg = 0; reg < 4; ++reg) {
    const float lq = __shfl(lv, hi * 4 + reg);  // sum for q = hi*4+reg
    const float inv = 1.f / lq;
    const int s = qt * 64 + w * 16 + hi * 4 + reg;
    short* op = PVb + (size_t)(b * S + s) * (H * D) + h * D;
#pragma unroll
    for (int n = 0; n < 4; ++n) op[n * 16 + lr] = f2bf(accO[n][reg] * inv);
  }
}

}  // namespace

extern "C" void kernel_launch(void* const* d_in, const int* in_sizes, int n_in,
                              void* d_out, int out_size, void* d_ws, size_t ws_size,
                              hipStream_t stream) {
  const float* x   = (const float*)d_in[0];
  const float* Wq  = (const float*)d_in[1];
  const float* Wk  = (const float*)d_in[2];
  const float* Wvd = (const float*)d_in[3];
  const float* Wvu = (const float*)d_in[4];
  const float* Wo  = (const float*)d_in[5];
  float* out = (float*)d_out;

  const size_t nqk = (size_t)B * H * S * D;  // 4.19M
  short* xb    = (short*)d_ws;
  short* Qb    = xb + nqk;
  short* Kb    = Qb + nqk;
  short* Vtg   = Kb + nqk;
  short* PVb   = Vtg + nqk;
  short* WcatT = PVb + nqk;            // [1536][512]
  short* W2T   = WcatT + 1536 * KD;    // [512][512]

  prep_kernel<<<dim3(2304), 256, 0, stream>>>(x, Wq, Wk, Wvd, Wvu, Wo,
                                              xb, WcatT, W2T);
  gemm_kernel<0><<<dim3(64, 12), 256, 0, stream>>>(xb, WcatT, Qb, Kb, Vtg, nullptr);
  attn_kernel<<<dim3(B * H, S / 64), 256, 0, stream>>>(Qb, Kb, Vtg, PVb);
  gemm_kernel<1><<<dim3(64, 4), 256, 0, stream>>>(PVb, W2T, nullptr, nullptr, nullptr, out);
}

// Round 9
// 85.148 us; speedup vs baseline: 1.4949x; 1.0055x over previous
//
#include <hip/hip_runtime.h>
#include <math.h>
#include <type_traits>

namespace {
constexpr int B = 4, S = 2048, E = 512, D = 64, H = 8;
constexpr int KD = 512;

typedef short bf8 __attribute__((ext_vector_type(8)));
typedef short bf4 __attribute__((ext_vector_type(4)));
typedef float f4 __attribute__((ext_vector_type(4)));

__device__ __forceinline__ short f2bf(float f) {
  union { float f; unsigned u; } v; v.f = f;
  const unsigned r = v.u + 0x7fffu + ((v.u >> 16) & 1u);  // RNE
  return (short)(r >> 16);
}

__device__ __forceinline__ unsigned cvt_pk_bf16(float a, float b) {
  unsigned r;
  asm("v_cvt_pk_bf16_f32 %0, %1, %2" : "=v"(r) : "v"(a), "v"(b));
  return r;  // lo16 = bf16(a), hi16 = bf16(b)
}

__device__ __forceinline__ void gload16(const void* g, void* l) {
  __builtin_amdgcn_global_load_lds(
      (const __attribute__((address_space(1))) unsigned int*)g,
      (__attribute__((address_space(3))) unsigned int*)l, 16, 0, 0);
}

// ---------------------------------------------------------------------------
// fused prep: [0,2048) xb convert; [2048,2240) WcatT; [2240,2304) W2T
// ---------------------------------------------------------------------------
__global__ __launch_bounds__(256) void prep_kernel(
    const float* __restrict__ x, const float* __restrict__ Wq,
    const float* __restrict__ Wk, const float* __restrict__ Wvd,
    const float* __restrict__ Wvu, const float* __restrict__ Wo,
    short* __restrict__ xb, short* __restrict__ WcatT,
    short* __restrict__ W2T) {
  __shared__ float T[64][65];
  const int bid = blockIdx.x;
  const int tid = threadIdx.x;
  if (bid < 2048) {
    const size_t i = ((size_t)bid * 256 + tid) * 8;
    const float4 v0 = *(const float4*)(x + i);
    const float4 v1 = *(const float4*)(x + i + 4);
    bf8 o;
    o[0] = f2bf(v0.x); o[1] = f2bf(v0.y); o[2] = f2bf(v0.z); o[3] = f2bf(v0.w);
    o[4] = f2bf(v1.x); o[5] = f2bf(v1.y); o[6] = f2bf(v1.z); o[7] = f2bf(v1.w);
    *(bf8*)(xb + i) = o;
  } else if (bid < 2240) {
    const int r = bid - 2048;
    const int cb = r >> 3, e0 = (r & 7) * 64;
    const int w = cb >> 3, h = cb & 7;
    const float* Wsel = (w == 0) ? Wq : (w == 1) ? Wk : Wvd;
    const float* Wp = Wsel + (size_t)h * E * D;
#pragma unroll
    for (int i = 0; i < 4; ++i) {
      const int f = tid + i * 256;
      const int rr = f >> 4, c4 = f & 15;
      const float4 v = *(const float4*)(Wp + (size_t)(e0 + rr) * D + c4 * 4);
      T[rr][c4 * 4 + 0] = v.x; T[rr][c4 * 4 + 1] = v.y;
      T[rr][c4 * 4 + 2] = v.z; T[rr][c4 * 4 + 3] = v.w;
    }
    __syncthreads();
#pragma unroll
    for (int i = 0; i < 4; ++i) {
      const int f = tid + i * 256;
      const int dr = f >> 4, e4 = f & 15;
      bf4 o;
#pragma unroll
      for (int j = 0; j < 4; ++j) o[j] = f2bf(T[e4 * 4 + j][dr]);
      *(bf4*)(WcatT + (size_t)(cb * 64 + dr) * KD + e0 + e4 * 4) = o;
    }
  } else {
    const int r = bid - 2240;
    const int h = r >> 3, e0 = (r & 7) * 64;
    const float wo = Wo[h];
#pragma unroll
    for (int i = 0; i < 4; ++i) {
      const int f = tid + i * 256;
      const int rr = f >> 4, c4 = f & 15;
      const float4 v = *(const float4*)(Wvu + ((size_t)h * D + rr) * E + e0 + c4 * 4);
      T[rr][c4 * 4 + 0] = v.x * wo; T[rr][c4 * 4 + 1] = v.y * wo;
      T[rr][c4 * 4 + 2] = v.z * wo; T[rr][c4 * 4 + 3] = v.w * wo;
    }
    __syncthreads();
#pragma unroll
    for (int i = 0; i < 4; ++i) {
      const int f = tid + i * 256;
      const int er = f >> 4, d4 = f & 15;
      bf4 o;
#pragma unroll
      for (int j = 0; j < 4; ++j) o[j] = f2bf(T[d4 * 4 + j][er]);
      *(bf4*)(W2T + (size_t)(e0 + er) * KD + h * 64 + d4 * 4) = o;
    }
  }
}

// ---------------------------------------------------------------------------
// bf16 MFMA GEMM.  MODE 0: proj -> Qb/Kb (row-major [bh][s][d]) and V^T
// (Vt[bh][d][s], bf4 packed stores).  MODE 1: out epilogue (fp32 row-major).
// ---------------------------------------------------------------------------
template <int MODE>
__global__ __launch_bounds__(256) void gemm_kernel(
    const short* __restrict__ A, const short* __restrict__ Bt,
    short* __restrict__ Qb, short* __restrict__ Kb, short* __restrict__ Vtg,
    float* __restrict__ Of) {
  const int row0 = blockIdx.x * 128;
  const int ct = blockIdx.y;
  const int tid = threadIdx.x;
  const int w = tid >> 6, l = tid & 63;
  const int wm = w >> 1, wn = w & 1;
  const int lr = l & 15, hi = l >> 4;

  __shared__ short As[128 * 64];
  __shared__ short Bs[128 * 64];

  const short* Ag = A + (size_t)row0 * KD;
  const short* Bg = Bt + (size_t)ct * 128 * KD;

  f4 acc[4][4] = {};
  for (int k0 = 0; k0 < KD; k0 += 64) {
    __syncthreads();
#pragma unroll
    for (int i = 0; i < 4; ++i) {
      const int f = i * 256 + tid;
      const int r = f >> 3, g = f & 7;
      gload16(Ag + (size_t)r * KD + k0 + ((g ^ (r & 7)) << 3), &As[f * 8]);
    }
#pragma unroll
    for (int i = 0; i < 4; ++i) {
      const int f = i * 256 + tid;
      const int r = f >> 3, g = f & 7;
      gload16(Bg + (size_t)r * KD + k0 + ((g ^ (r & 7)) << 3), &Bs[f * 8]);
    }
    __syncthreads();

    bf8 af[4][2], bfv[4][2];
#pragma unroll
    for (int t = 0; t < 4; ++t) {
#pragma unroll
      for (int kh = 0; kh < 2; ++kh) {
        const int ar = wm * 64 + t * 16 + lr;
        af[t][kh] = *(const bf8*)&As[ar * 64 + (((kh * 4 + hi) ^ (ar & 7)) << 3)];
        const int br = wn * 64 + t * 16 + lr;
        bfv[t][kh] = *(const bf8*)&Bs[br * 64 + (((kh * 4 + hi) ^ (br & 7)) << 3)];
      }
    }
#pragma unroll
    for (int mt = 0; mt < 4; ++mt)
#pragma unroll
      for (int nt = 0; nt < 4; ++nt) {
        acc[mt][nt] =
            __builtin_amdgcn_mfma_f32_16x16x32_bf16(af[mt][0], bfv[nt][0], acc[mt][nt], 0, 0, 0);
        acc[mt][nt] =
            __builtin_amdgcn_mfma_f32_16x16x32_bf16(af[mt][1], bfv[nt][1], acc[mt][nt], 0, 0, 0);
      }
  }

  if constexpr (MODE == 0) {
#pragma unroll
    for (int nt = 0; nt < 4; ++nt) {
      const int gc = ct * 128 + wn * 64 + nt * 16 + lr;
      const int cb = gc >> 6, d = gc & 63;
      const int h = cb & 7;
      if (cb < 16) {
        short* Out = (cb < 8) ? Qb : Kb;
#pragma unroll
        for (int mt = 0; mt < 4; ++mt)
#pragma unroll
          for (int reg = 0; reg < 4; ++reg) {
            const int grow = row0 + wm * 64 + mt * 16 + hi * 4 + reg;
            const int b = grow >> 11, s = grow & (S - 1);
            Out[(((size_t)(b * H + h) * S + s) << 6) + d] = f2bf(acc[mt][nt][reg]);
          }
      } else {
        // V^T: Vt[bh][d][s], 4 consecutive s per lane -> packed bf4 store
#pragma unroll
        for (int mt = 0; mt < 4; ++mt) {
          const int grow0 = row0 + wm * 64 + mt * 16 + hi * 4;
          const int b = grow0 >> 11, s0 = grow0 & (S - 1);
          bf4 o;
#pragma unroll
          for (int reg = 0; reg < 4; ++reg) o[reg] = f2bf(acc[mt][nt][reg]);
          *(bf4*)(Vtg + (((size_t)(b * H + h) * D + d) << 11) + s0) = o;
        }
      }
    }
  } else {
#pragma unroll
    for (int mt = 0; mt < 4; ++mt)
#pragma unroll
      for (int reg = 0; reg < 4; ++reg) {
        const int grow = row0 + wm * 64 + mt * 16 + hi * 4 + reg;
        float* orow = Of + (size_t)grow * 512 + ct * 128 + wn * 64;
#pragma unroll
        for (int nt = 0; nt < 4; ++nt) orow[nt * 16 + lr] = acc[mt][nt][reg];
      }
  }
}

// ---------------------------------------------------------------------------
// attn v6: swapped QK^T + fixed-max softmax + counted-vmcnt dbuf pipeline +
// IN-REGISTER P: cvt_pk output feeds v_mfma_f32_16x16x16_bf16 directly as the
// A-fragment (m=q, k=hi*4+i matches the swapped-QK^T accumulator layout).
// No P LDS round-trip; LDS 32KB -> 5 blocks/CU.
// Masking replicates reference: (t<=q) && (raw score != 0), else p=0.
// ---------------------------------------------------------------------------
__global__ __launch_bounds__(256) void attn_kernel(
    const short* __restrict__ Qb, const short* __restrict__ Kb,
    const short* __restrict__ Vt, short* __restrict__ PVb) {
  const int bh = blockIdx.x;
  const int qt = (int)(gridDim.y - 1 - blockIdx.y);  // longest-first
  const int b = bh >> 3, h = bh & 7;
  const int tid = threadIdx.x;
  const int w = tid >> 6, l = tid & 63;
  const int lr = l & 15, hi = l >> 4;

  __shared__ short KsA[64 * 64];
  __shared__ short KsB[64 * 64];
  __shared__ short VsA[64 * 64];
  __shared__ short VsB[64 * 64];

  // Q fragment (B operand after swap): col q = lr, k = kh*32 + hi*8 + j
  const short* Qg = Qb + ((size_t)bh * S + qt * 64 + w * 16 + lr) * D;
  const bf8 qf0 = *(const bf8*)(Qg + hi * 8);
  const bf8 qf1 = *(const bf8*)(Qg + 32 + hi * 8);

  const short* Kg = Kb + (size_t)bh * S * D;   // [t][64]
  const short* Vg = Vt + (size_t)bh * D * S;   // [e][S]

  const int sr = tid >> 3, sg = tid & 7;
  const int sswz = (sg ^ (sr & 7)) << 3;
  const int sr2 = sr + 32, sswz2 = (sg ^ (sr2 & 7)) << 3;

  // staging pointers, advanced by one tile per iteration
  const short* kg0 = Kg + (size_t)sr * D + sswz;
  const short* kg1 = Kg + (size_t)sr2 * D + sswz2;
  const short* vg0 = Vg + (size_t)sr * S + sswz;
  const short* vg1 = Vg + (size_t)sr2 * S + sswz2;

  float lsum4[4] = {};  // per-reg partial denominators (independent chains)
  f4 accO[4] = {};      // O[q = hi*4+reg][e = n*16+lr]

  constexpr float LOG2E = 1.44269504088896340736f;
  constexpr float C1 = 0.125f * LOG2E;
  constexpr float C0 = -12.0f * LOG2E;

  auto step = [&](const short* Kl, const short* Vl, auto diag_c) {
    constexpr bool DIAG = decltype(diag_c)::value;
    // QK^T swapped: A = K (rows t), B = Q (cols q) -> D[t][q]
    f4 accS[4] = {};
    __builtin_amdgcn_s_setprio(1);
#pragma unroll
    for (int n = 0; n < 4; ++n) {
      const int tr = n * 16 + lr;
      const bf8 k0 = *(const bf8*)&Kl[tr * 64 + ((hi ^ (tr & 7)) << 3)];
      const bf8 k1 = *(const bf8*)&Kl[tr * 64 + (((4 + hi) ^ (tr & 7)) << 3)];
      accS[n] = __builtin_amdgcn_mfma_f32_16x16x32_bf16(k0, qf0, accS[n], 0, 0, 0);
      accS[n] = __builtin_amdgcn_mfma_f32_16x16x32_bf16(k1, qf1, accS[n], 0, 0, 0);
    }
    __builtin_amdgcn_s_setprio(0);

    // p = exp2(sv*C1 + C0), masked; lane's 4 regs = 4 consecutive t, q = lr.
    // cvt_pk output pair IS the 16x16x16 A-fragment (m=q, k=hi*4+i).
    bf4 pa[4];
#pragma unroll
    for (int n = 0; n < 4; ++n) {
      float p[4];
#pragma unroll
      for (int reg = 0; reg < 4; ++reg) {
        const float sv = accS[n][reg];
        bool ok = (sv != 0.f);
        if constexpr (DIAG) ok = ok && (n * 16 + hi * 4 + reg <= w * 16 + lr);
        p[reg] = ok ? exp2f(fmaf(sv, C1, C0)) : 0.f;
        lsum4[reg] += p[reg];
      }
      union { int2 i; bf4 v; } u;
      u.i.x = (int)cvt_pk_bf16(p[0], p[1]);
      u.i.y = (int)cvt_pk_bf16(p[2], p[3]);
      pa[n] = u.v;
    }

    // PV: O[q][e] += sum_n' P16[n'] @ V16[n'], K=16 MFMA, A from registers.
    // B-fragment: col n = lr (e), k = hi*4+j -> Vt[e][n'*16+hi*4 .. +3] (b64)
    __builtin_amdgcn_s_setprio(1);
#pragma unroll
    for (int np = 0; np < 4; ++np) {
      const int gb = 2 * np + (hi >> 1);     // t-granule of this k-slice
      const int ho = (hi & 1) << 2;          // half-granule offset (shorts)
#pragma unroll
      for (int ne = 0; ne < 4; ++ne) {
        const int er = ne * 16 + lr;
        const bf4 vf = *(const bf4*)&Vl[er * 64 + ((gb ^ (er & 7)) << 3) + ho];
        accO[ne] = __builtin_amdgcn_mfma_f32_16x16x16bf16_1k(pa[np], vf, accO[ne], 0, 0, 0);
      }
    }
    __builtin_amdgcn_s_setprio(0);
  };

  // prologue: issue tile-0 loads
  gload16(kg0, &KsA[tid * 8]);
  gload16(kg1, &KsA[(256 + tid) * 8]);
  gload16(vg0, &VsA[tid * 8]);
  gload16(vg1, &VsA[(256 + tid) * 8]);
  kg0 += 64 * D; kg1 += 64 * D; vg0 += 64; vg1 += 64;

  short* Kc = KsA; short* Vc = VsA;
  short* Kn = KsB; short* Vn = VsB;

  for (int kt = 0; kt <= qt; ++kt) {
    if (kt > 0) {
      __builtin_amdgcn_s_barrier();   // all waves done reading Kn/Vn's old data
      __builtin_amdgcn_sched_barrier(0);
    }
    if (kt < qt) {
      gload16(kg0, &Kn[tid * 8]);
      gload16(kg1, &Kn[(256 + tid) * 8]);
      gload16(vg0, &Vn[tid * 8]);
      gload16(vg1, &Vn[(256 + tid) * 8]);
      kg0 += 64 * D; kg1 += 64 * D; vg0 += 64; vg1 += 64;
      asm volatile("s_waitcnt vmcnt(4)" ::: "memory");  // tile-kt loads done
    } else {
      asm volatile("s_waitcnt vmcnt(0)" ::: "memory");
    }
    __builtin_amdgcn_sched_barrier(0);
    __builtin_amdgcn_s_barrier();     // all waves' tile-kt loads visible
    __builtin_amdgcn_sched_barrier(0);

    if (kt < qt) {
      step(Kc, Vc, std::integral_constant<bool, false>{});
    } else {
      step(Kc, Vc, std::integral_constant<bool, true>{});
    }
    { short* t = Kc; Kc = Kn; Kn = t; t = Vc; Vc = Vn; Vn = t; }
  }

  // epilogue: finish denominator (sum over hi-groups), redistribute, store
  float lv = (lsum4[0] + lsum4[1]) + (lsum4[2] + lsum4[3]);
  lv += __shfl_xor(lv, 16);
  lv += __shfl_xor(lv, 32);   // all lanes now hold full sum for q = lr
#pragma unroll
  for (int reg = 0; reg < 4; ++reg) {
    const float lq = __shfl(lv, hi * 4 + reg);  // sum for q = hi*4+reg
    const float inv = 1.f / lq;
    const int s = qt * 64 + w * 16 + hi * 4 + reg;
    short* op = PVb + (size_t)(b * S + s) * (H * D) + h * D;
#pragma unroll
    for (int n = 0; n < 4; ++n) op[n * 16 + lr] = f2bf(accO[n][reg] * inv);
  }
}

}  // namespace

extern "C" void kernel_launch(void* const* d_in, const int* in_sizes, int n_in,
                              void* d_out, int out_size, void* d_ws, size_t ws_size,
                              hipStream_t stream) {
  const float* x   = (const float*)d_in[0];
  const float* Wq  = (const float*)d_in[1];
  const float* Wk  = (const float*)d_in[2];
  const float* Wvd = (const float*)d_in[3];
  const float* Wvu = (const float*)d_in[4];
  const float* Wo  = (const float*)d_in[5];
  float* out = (float*)d_out;

  const size_t nqk = (size_t)B * H * S * D;  // 4.19M
  short* xb    = (short*)d_ws;
  short* Qb    = xb + nqk;
  short* Kb    = Qb + nqk;
  short* Vtg   = Kb + nqk;
  short* PVb   = Vtg + nqk;
  short* WcatT = PVb + nqk;            // [1536][512]
  short* W2T   = WcatT + 1536 * KD;    // [512][512]

  prep_kernel<<<dim3(2304), 256, 0, stream>>>(x, Wq, Wk, Wvd, Wvu, Wo,
                                              xb, WcatT, W2T);
  gemm_kernel<0><<<dim3(64, 12), 256, 0, stream>>>(xb, WcatT, Qb, Kb, Vtg, nullptr);
  attn_kernel<<<dim3(B * H, S / 64), 256, 0, stream>>>(Qb, Kb, Vtg, PVb);
  gemm_kernel<1><<<dim3(64, 4), 256, 0, stream>>>(PVb, W2T, nullptr, nullptr, nullptr, out);
}

// Round 10
// 81.049 us; speedup vs baseline: 1.5705x; 1.0506x over previous
//
#include <hip/hip_runtime.h>
#include <math.h>
#include <type_traits>

namespace {
constexpr int B = 4, S = 2048, E = 512, D = 64, H = 8;
constexpr int KD = 512;

typedef short bf8 __attribute__((ext_vector_type(8)));
typedef short bf4 __attribute__((ext_vector_type(4)));
typedef float f4 __attribute__((ext_vector_type(4)));

__device__ __forceinline__ short f2bf(float f) {
  union { float f; unsigned u; } v; v.f = f;
  const unsigned r = v.u + 0x7fffu + ((v.u >> 16) & 1u);  // RNE
  return (short)(r >> 16);
}

__device__ __forceinline__ unsigned cvt_pk_bf16(float a, float b) {
  unsigned r;
  asm("v_cvt_pk_bf16_f32 %0, %1, %2" : "=v"(r) : "v"(a), "v"(b));
  return r;  // lo16 = bf16(a), hi16 = bf16(b)
}

__device__ __forceinline__ void gload16(const void* g, void* l) {
  __builtin_amdgcn_global_load_lds(
      (const __attribute__((address_space(1))) unsigned int*)g,
      (__attribute__((address_space(3))) unsigned int*)l, 16, 0, 0);
}

// ---------------------------------------------------------------------------
// fused prep: [0,2048) xb convert; [2048,2240) WcatT; [2240,2304) W2T
// ---------------------------------------------------------------------------
__global__ __launch_bounds__(256) void prep_kernel(
    const float* __restrict__ x, const float* __restrict__ Wq,
    const float* __restrict__ Wk, const float* __restrict__ Wvd,
    const float* __restrict__ Wvu, const float* __restrict__ Wo,
    short* __restrict__ xb, short* __restrict__ WcatT,
    short* __restrict__ W2T) {
  __shared__ float T[64][65];
  const int bid = blockIdx.x;
  const int tid = threadIdx.x;
  if (bid < 2048) {
    const size_t i = ((size_t)bid * 256 + tid) * 8;
    const float4 v0 = *(const float4*)(x + i);
    const float4 v1 = *(const float4*)(x + i + 4);
    bf8 o;
    o[0] = f2bf(v0.x); o[1] = f2bf(v0.y); o[2] = f2bf(v0.z); o[3] = f2bf(v0.w);
    o[4] = f2bf(v1.x); o[5] = f2bf(v1.y); o[6] = f2bf(v1.z); o[7] = f2bf(v1.w);
    *(bf8*)(xb + i) = o;
  } else if (bid < 2240) {
    const int r = bid - 2048;
    const int cb = r >> 3, e0 = (r & 7) * 64;
    const int w = cb >> 3, h = cb & 7;
    const float* Wsel = (w == 0) ? Wq : (w == 1) ? Wk : Wvd;
    const float* Wp = Wsel + (size_t)h * E * D;
#pragma unroll
    for (int i = 0; i < 4; ++i) {
      const int f = tid + i * 256;
      const int rr = f >> 4, c4 = f & 15;
      const float4 v = *(const float4*)(Wp + (size_t)(e0 + rr) * D + c4 * 4);
      T[rr][c4 * 4 + 0] = v.x; T[rr][c4 * 4 + 1] = v.y;
      T[rr][c4 * 4 + 2] = v.z; T[rr][c4 * 4 + 3] = v.w;
    }
    __syncthreads();
#pragma unroll
    for (int i = 0; i < 4; ++i) {
      const int f = tid + i * 256;
      const int dr = f >> 4, e4 = f & 15;
      bf4 o;
#pragma unroll
      for (int j = 0; j < 4; ++j) o[j] = f2bf(T[e4 * 4 + j][dr]);
      *(bf4*)(WcatT + (size_t)(cb * 64 + dr) * KD + e0 + e4 * 4) = o;
    }
  } else {
    const int r = bid - 2240;
    const int h = r >> 3, e0 = (r & 7) * 64;
    const float wo = Wo[h];
#pragma unroll
    for (int i = 0; i < 4; ++i) {
      const int f = tid + i * 256;
      const int rr = f >> 4, c4 = f & 15;
      const float4 v = *(const float4*)(Wvu + ((size_t)h * D + rr) * E + e0 + c4 * 4);
      T[rr][c4 * 4 + 0] = v.x * wo; T[rr][c4 * 4 + 1] = v.y * wo;
      T[rr][c4 * 4 + 2] = v.z * wo; T[rr][c4 * 4 + 3] = v.w * wo;
    }
    __syncthreads();
#pragma unroll
    for (int i = 0; i < 4; ++i) {
      const int f = tid + i * 256;
      const int er = f >> 4, d4 = f & 15;
      bf4 o;
#pragma unroll
      for (int j = 0; j < 4; ++j) o[j] = f2bf(T[d4 * 4 + j][er]);
      *(bf4*)(W2T + (size_t)(e0 + er) * KD + h * 64 + d4 * 4) = o;
    }
  }
}

// ---------------------------------------------------------------------------
// bf16 MFMA GEMM.  MODE 0: proj -> Qb/Kb (row-major [bh][s][d]) and V^T
// (Vt[bh][d][s], bf4 stores; 8B halves of each 16B granule swapped for rows
// with (d>>3)&1 -- bank-spread permutation consumed by attn).
// MODE 1: out epilogue (fp32 row-major).
// ---------------------------------------------------------------------------
template <int MODE>
__global__ __launch_bounds__(256) void gemm_kernel(
    const short* __restrict__ A, const short* __restrict__ Bt,
    short* __restrict__ Qb, short* __restrict__ Kb, short* __restrict__ Vtg,
    float* __restrict__ Of) {
  const int row0 = blockIdx.x * 128;
  const int ct = blockIdx.y;
  const int tid = threadIdx.x;
  const int w = tid >> 6, l = tid & 63;
  const int wm = w >> 1, wn = w & 1;
  const int lr = l & 15, hi = l >> 4;

  __shared__ short As[128 * 64];
  __shared__ short Bs[128 * 64];

  const short* Ag = A + (size_t)row0 * KD;
  const short* Bg = Bt + (size_t)ct * 128 * KD;

  f4 acc[4][4] = {};
  for (int k0 = 0; k0 < KD; k0 += 64) {
    __syncthreads();
#pragma unroll
    for (int i = 0; i < 4; ++i) {
      const int f = i * 256 + tid;
      const int r = f >> 3, g = f & 7;
      gload16(Ag + (size_t)r * KD + k0 + ((g ^ (r & 7)) << 3), &As[f * 8]);
    }
#pragma unroll
    for (int i = 0; i < 4; ++i) {
      const int f = i * 256 + tid;
      const int r = f >> 3, g = f & 7;
      gload16(Bg + (size_t)r * KD + k0 + ((g ^ (r & 7)) << 3), &Bs[f * 8]);
    }
    __syncthreads();

    bf8 af[4][2], bfv[4][2];
#pragma unroll
    for (int t = 0; t < 4; ++t) {
#pragma unroll
      for (int kh = 0; kh < 2; ++kh) {
        const int ar = wm * 64 + t * 16 + lr;
        af[t][kh] = *(const bf8*)&As[ar * 64 + (((kh * 4 + hi) ^ (ar & 7)) << 3)];
        const int br = wn * 64 + t * 16 + lr;
        bfv[t][kh] = *(const bf8*)&Bs[br * 64 + (((kh * 4 + hi) ^ (br & 7)) << 3)];
      }
    }
#pragma unroll
    for (int mt = 0; mt < 4; ++mt)
#pragma unroll
      for (int nt = 0; nt < 4; ++nt) {
        acc[mt][nt] =
            __builtin_amdgcn_mfma_f32_16x16x32_bf16(af[mt][0], bfv[nt][0], acc[mt][nt], 0, 0, 0);
        acc[mt][nt] =
            __builtin_amdgcn_mfma_f32_16x16x32_bf16(af[mt][1], bfv[nt][1], acc[mt][nt], 0, 0, 0);
      }
  }

  if constexpr (MODE == 0) {
#pragma unroll
    for (int nt = 0; nt < 4; ++nt) {
      const int gc = ct * 128 + wn * 64 + nt * 16 + lr;
      const int cb = gc >> 6, d = gc & 63;
      const int h = cb & 7;
      if (cb < 16) {
        short* Out = (cb < 8) ? Qb : Kb;
#pragma unroll
        for (int mt = 0; mt < 4; ++mt)
#pragma unroll
          for (int reg = 0; reg < 4; ++reg) {
            const int grow = row0 + wm * 64 + mt * 16 + hi * 4 + reg;
            const int b = grow >> 11, s = grow & (S - 1);
            Out[(((size_t)(b * H + h) * S + s) << 6) + d] = f2bf(acc[mt][nt][reg]);
          }
      } else {
        // V^T: Vt[bh][d][s]; swap 8B halves within 16B granules on rows
        // with (d>>3)&1 to spread LDS banks for attn's b64 reads.
        const int hswap = ((d >> 3) & 1) << 2;
#pragma unroll
        for (int mt = 0; mt < 4; ++mt) {
          const int grow0 = row0 + wm * 64 + mt * 16 + hi * 4;
          const int b = grow0 >> 11, s0 = (grow0 & (S - 1)) ^ hswap;
          bf4 o;
#pragma unroll
          for (int reg = 0; reg < 4; ++reg) o[reg] = f2bf(acc[mt][nt][reg]);
          *(bf4*)(Vtg + (((size_t)(b * H + h) * D + d) << 11) + s0) = o;
        }
      }
    }
  } else {
#pragma unroll
    for (int mt = 0; mt < 4; ++mt)
#pragma unroll
      for (int reg = 0; reg < 4; ++reg) {
        const int grow = row0 + wm * 64 + mt * 16 + hi * 4 + reg;
        float* orow = Of + (size_t)grow * 512 + ct * 128 + wn * 64;
#pragma unroll
        for (int nt = 0; nt < 4; ++nt) orow[nt * 16 + lr] = acc[mt][nt][reg];
      }
  }
}

// ---------------------------------------------------------------------------
// attn v7: balanced triangle pairing. Block (bh, j) processes q-tile j
// (j+1 K-tiles) then q-tile 31-j (32-j K-tiles) -> every block 33 steps.
// Swapped QK^T, fixed-max softmax (M=12), in-register P (K=16 PV MFMA),
// counted-vmcnt dbuf pipeline, precomputed lane-constant LDS offsets.
// Masking: diag tiles apply t<=q; interior tiles all-valid.
// ---------------------------------------------------------------------------
__global__ __launch_bounds__(256) void attn_kernel(
    const short* __restrict__ Qb, const short* __restrict__ Kb,
    const short* __restrict__ Vt, short* __restrict__ PVb) {
  const int bh = blockIdx.x;
  const int j = blockIdx.y;            // pair index 0..15
  const int qtA = j, qtB = 31 - j;
  const int nA = j + 1;                // steps in phase A (33 total)
  const int b = bh >> 3, h = bh & 7;
  const int tid = threadIdx.x;
  const int w = tid >> 6, l = tid & 63;
  const int lr = l & 15, hi = l >> 4;

  __shared__ short Ks[2][64 * 64];
  __shared__ short Vs[2][64 * 64];

  // Q fragments (B operand of swapped QK^T) for both phases
  const short* QgA = Qb + ((size_t)bh * S + qtA * 64 + w * 16 + lr) * D;
  const short* QgB = Qb + ((size_t)bh * S + qtB * 64 + w * 16 + lr) * D;
  const bf8 qA0 = *(const bf8*)(QgA + hi * 8);
  const bf8 qA1 = *(const bf8*)(QgA + 32 + hi * 8);
  const bf8 qB0 = *(const bf8*)(QgB + hi * 8);
  const bf8 qB1 = *(const bf8*)(QgB + 32 + hi * 8);

  const short* Kg = Kb + (size_t)bh * S * D;   // [t][64]
  const short* Vg = Vt + (size_t)bh * D * S;   // [e][S] (half-swapped rows)

  // staging lane addresses (fixed; tile offset added per step)
  const int sr = tid >> 3, sg = tid & 7;
  const int sswz = (sg ^ (sr & 7)) << 3;
  const int sr2 = sr + 32, sswz2 = (sg ^ (sr2 & 7)) << 3;
  const short* kg0 = Kg + (size_t)sr * D + sswz;
  const short* kg1 = Kg + (size_t)sr2 * D + sswz2;
  const short* vg0 = Vg + (size_t)sr * S + sswz;
  const short* vg1 = Vg + (size_t)sr2 * S + sswz2;

  // precomputed lane-constant LDS byte offsets
  const int e7 = lr & 7;
  const int kla0 = lr * 128 + ((hi ^ e7) << 4);
  const int kla1 = kla0 ^ 64;
  const int x7 = (hi >> 1) ^ e7;
  const int swaph = ((hi & 1) ^ ((lr >> 3) & 1)) << 3;
  int vla[4];
#pragma unroll
  for (int np = 0; np < 4; ++np)
    vla[np] = lr * 128 + (((2 * np) ^ x7) << 4) + swaph;

  float lsum4[4] = {};
  f4 accO[4] = {};

  auto step = [&](int buf, bf8 q0, bf8 q1, auto diag_c) {
    constexpr bool DIAG = decltype(diag_c)::value;
    const char* Klb = (const char*)Ks[buf];
    const char* Vlb = (const char*)Vs[buf];
    // QK^T swapped: A = K (rows t), B = Q (cols q) -> D[t][q]
    f4 accS[4] = {};
    __builtin_amdgcn_s_setprio(1);
#pragma unroll
    for (int n = 0; n < 4; ++n) {
      const bf8 k0 = *(const bf8*)(Klb + kla0 + n * 2048);
      const bf8 k1 = *(const bf8*)(Klb + kla1 + n * 2048);
      accS[n] = __builtin_amdgcn_mfma_f32_16x16x32_bf16(k0, q0, accS[n], 0, 0, 0);
      accS[n] = __builtin_amdgcn_mfma_f32_16x16x32_bf16(k1, q1, accS[n], 0, 0, 0);
    }
    __builtin_amdgcn_s_setprio(0);

    // p = exp(sv*0.125 - 12) (fixed-max softmax); diag applies causal mask
    bf4 pa[4];
#pragma unroll
    for (int n = 0; n < 4; ++n) {
      float p[4];
#pragma unroll
      for (int reg = 0; reg < 4; ++reg) {
        float pv = __expf(fmaf(accS[n][reg], 0.125f, -12.0f));
        if constexpr (DIAG) {
          const bool ok = (n * 16 + hi * 4 + reg) <= (w * 16 + lr);
          pv = ok ? pv : 0.f;
        }
        p[reg] = pv;
        lsum4[reg] += pv;
      }
      union { int2 i; bf4 v; } u;
      u.i.x = (int)cvt_pk_bf16(p[0], p[1]);
      u.i.y = (int)cvt_pk_bf16(p[2], p[3]);
      pa[n] = u.v;
    }

    // PV: O[q][e] += P16[np] @ V16[np], A from registers, B b64 from LDS
    __builtin_amdgcn_s_setprio(1);
#pragma unroll
    for (int np = 0; np < 4; ++np) {
#pragma unroll
      for (int ne = 0; ne < 4; ++ne) {
        const bf4 vf = *(const bf4*)(Vlb + vla[np] + ne * 2048);
        accO[ne] = __builtin_amdgcn_mfma_f32_16x16x16bf16_1k(pa[np], vf, accO[ne], 0, 0, 0);
      }
    }
    __builtin_amdgcn_s_setprio(0);
  };

  auto epi = [&](int qt) {
    float lv = (lsum4[0] + lsum4[1]) + (lsum4[2] + lsum4[3]);
    lv += __shfl_xor(lv, 16);
    lv += __shfl_xor(lv, 32);   // all lanes: full denominator for q = lr
#pragma unroll
    for (int reg = 0; reg < 4; ++reg) {
      const float lq = __shfl(lv, hi * 4 + reg);
      const float inv = 1.f / lq;
      const int s = qt * 64 + w * 16 + hi * 4 + reg;
      short* op = PVb + (size_t)(b * S + s) * (H * D) + h * D;
#pragma unroll
      for (int n = 0; n < 4; ++n) op[n * 16 + lr] = f2bf(accO[n][reg] * inv);
    }
  };

  // prologue: stage tile 0 (phase A kt=0) into buf 0
  gload16(kg0, &Ks[0][tid * 8]);
  gload16(kg1, &Ks[0][(256 + tid) * 8]);
  gload16(vg0, &Vs[0][tid * 8]);
  gload16(vg1, &Vs[0][(256 + tid) * 8]);

  int buf = 0;
  for (int s = 0; s < 33; ++s) {
    if (s > 0) {
      __builtin_amdgcn_s_barrier();   // all waves done reading next buffer's old data
      __builtin_amdgcn_sched_barrier(0);
    }
    if (s < 32) {
      const int ktn = (s + 1 < nA) ? s + 1 : s + 1 - nA;  // next tile index
      const size_t ko = (size_t)ktn << 12;  // shorts: ktn*64 rows * 64
      const size_t vo = (size_t)ktn << 6;   // shorts: ktn*64 cols
      const int nb = buf ^ 1;
      gload16(kg0 + ko, &Ks[nb][tid * 8]);
      gload16(kg1 + ko, &Ks[nb][(256 + tid) * 8]);
      gload16(vg0 + vo, &Vs[nb][tid * 8]);
      gload16(vg1 + vo, &Vs[nb][(256 + tid) * 8]);
      asm volatile("s_waitcnt vmcnt(4)" ::: "memory");  // current tile's loads done
    } else {
      asm volatile("s_waitcnt vmcnt(0)" ::: "memory");
    }
    __builtin_amdgcn_sched_barrier(0);
    __builtin_amdgcn_s_barrier();     // all waves' current-tile loads visible
    __builtin_amdgcn_sched_barrier(0);

    if (s < nA) {
      if (s == nA - 1) step(buf, qA0, qA1, std::true_type{});
      else             step(buf, qA0, qA1, std::false_type{});
    } else {
      if (s == 32)     step(buf, qB0, qB1, std::true_type{});
      else             step(buf, qB0, qB1, std::false_type{});
    }

    if (s == nA - 1) {  // phase A done: write its output, reset state
      epi(qtA);
#pragma unroll
      for (int n = 0; n < 4; ++n) accO[n] = f4{0.f, 0.f, 0.f, 0.f};
      lsum4[0] = lsum4[1] = lsum4[2] = lsum4[3] = 0.f;
    }
    buf ^= 1;
  }
  epi(qtB);
}

}  // namespace

extern "C" void kernel_launch(void* const* d_in, const int* in_sizes, int n_in,
                              void* d_out, int out_size, void* d_ws, size_t ws_size,
                              hipStream_t stream) {
  const float* x   = (const float*)d_in[0];
  const float* Wq  = (const float*)d_in[1];
  const float* Wk  = (const float*)d_in[2];
  const float* Wvd = (const float*)d_in[3];
  const float* Wvu = (const float*)d_in[4];
  const float* Wo  = (const float*)d_in[5];
  float* out = (float*)d_out;

  const size_t nqk = (size_t)B * H * S * D;  // 4.19M
  short* xb    = (short*)d_ws;
  short* Qb    = xb + nqk;
  short* Kb    = Qb + nqk;
  short* Vtg   = Kb + nqk;
  short* PVb   = Vtg + nqk;
  short* WcatT = PVb + nqk;            // [1536][512]
  short* W2T   = WcatT + 1536 * KD;    // [512][512]

  prep_kernel<<<dim3(2304), 256, 0, stream>>>(x, Wq, Wk, Wvd, Wvu, Wo,
                                              xb, WcatT, W2T);
  gemm_kernel<0><<<dim3(64, 12), 256, 0, stream>>>(xb, WcatT, Qb, Kb, Vtg, nullptr);
  attn_kernel<<<dim3(B * H, 16), 256, 0, stream>>>(Qb, Kb, Vtg, PVb);
  gemm_kernel<1><<<dim3(64, 4), 256, 0, stream>>>(PVb, W2T, nullptr, nullptr, nullptr, out);
}